// Round 1
// baseline (1957.289 us; speedup 1.0000x reference)
//
#include <hip/hip_runtime.h>

#define N_NODES 100000
#define N_EDGES 3200000
#define IN_DIM  128
#define HEADS   4
#define OUT_DIM 64   // HEADS * 16
#define NEG_SLOPE 0.2f

// ---- monotone uint encoding of float for atomicMax ----
__device__ inline unsigned int fenc(float f) {
    unsigned int b = __float_as_uint(f);
    return (b & 0x80000000u) ? ~b : (b | 0x80000000u);
}
__device__ inline float fdec(unsigned int k) {
    return __uint_as_float((k & 0x80000000u) ? (k & 0x7FFFFFFFu) : ~k);
}

// K1: feat[n][o] = dot(h[n,:], W[o,:]); el[n][h] = sum_d feat*attn_l; er likewise
__global__ __launch_bounds__(256) void gat_gemm(
    const float* __restrict__ h, const float* __restrict__ W,
    const float* __restrict__ attn_l, const float* __restrict__ attn_r,
    float* __restrict__ feat, float* __restrict__ el, float* __restrict__ er) {
    __shared__ float Ws[OUT_DIM][IN_DIM + 1];   // +1 pad: kills 32-way conflict
    __shared__ float Hs[16][IN_DIM];
    const int tid = threadIdx.x;

    for (int i = tid * 4; i < OUT_DIM * IN_DIM; i += 256 * 4) {
        float4 w4 = *reinterpret_cast<const float4*>(W + i);
        int o = i >> 7, k = i & 127;
        Ws[o][k] = w4.x; Ws[o][k + 1] = w4.y; Ws[o][k + 2] = w4.z; Ws[o][k + 3] = w4.w;
    }
    const int base = blockIdx.x * 16;
    for (int i = tid * 4; i < 16 * IN_DIM; i += 256 * 4) {
        int nl = i >> 7, k = i & 127;
        *reinterpret_cast<float4*>(&Hs[nl][k]) =
            *reinterpret_cast<const float4*>(h + (size_t)(base + nl) * IN_DIM + k);
    }
    __syncthreads();

    const int o = tid & 63;
    const float al = attn_l[o], ar = attn_r[o];
    #pragma unroll
    for (int it = 0; it < 4; ++it) {
        const int nl = it * 4 + (tid >> 6);
        float acc = 0.f;
        #pragma unroll
        for (int k = 0; k < IN_DIM; ++k)
            acc = fmaf(Hs[nl][k], Ws[o][k], acc);
        const int n = base + nl;
        feat[(size_t)n * OUT_DIM + o] = acc;
        float vl = acc * al, vr = acc * ar;
        #pragma unroll
        for (int off = 8; off >= 1; off >>= 1) {
            vl += __shfl_xor(vl, off, 16);
            vr += __shfl_xor(vr, off, 16);
        }
        if ((o & 15) == 0) {
            const int hh = o >> 4;
            el[n * HEADS + hh] = vl;
            er[n * HEADS + hh] = vr;
        }
    }
}

// K2: init out=bias, m=enc(-inf-ish)=0, s=0
__global__ __launch_bounds__(256) void gat_init(
    float* __restrict__ out, const float* __restrict__ bias,
    unsigned int* __restrict__ m, float* __restrict__ s) {
    int i = blockIdx.x * 256 + threadIdx.x;
    if (i < N_NODES * OUT_DIM) out[i] = bias[i & 63];
    if (i < N_NODES * HEADS) { m[i] = 0u; s[i] = 0.f; }
}

// K3: segment max of leaky-relu scores
__global__ __launch_bounds__(256) void gat_edge_max(
    const int* __restrict__ src, const int* __restrict__ dst,
    const float* __restrict__ el, const float* __restrict__ er,
    unsigned int* __restrict__ m) {
    int e = blockIdx.x * 256 + threadIdx.x;
    if (e >= N_EDGES) return;
    int sn = src[e], dn = dst[e];
    float4 l = *reinterpret_cast<const float4*>(el + sn * 4);
    float4 r = *reinterpret_cast<const float4*>(er + dn * 4);
    const float* lp = reinterpret_cast<const float*>(&l);
    const float* rp = reinterpret_cast<const float*>(&r);
    #pragma unroll
    for (int hh = 0; hh < HEADS; ++hh) {
        float sc = lp[hh] + rp[hh];
        sc = sc > 0.f ? sc : NEG_SLOPE * sc;
        atomicMax(m + dn * 4 + hh, fenc(sc));
    }
}

// K4: segment sum of exp(score - m)
__global__ __launch_bounds__(256) void gat_edge_sum(
    const int* __restrict__ src, const int* __restrict__ dst,
    const float* __restrict__ el, const float* __restrict__ er,
    const unsigned int* __restrict__ m, float* __restrict__ s) {
    int e = blockIdx.x * 256 + threadIdx.x;
    if (e >= N_EDGES) return;
    int sn = src[e], dn = dst[e];
    float4 l = *reinterpret_cast<const float4*>(el + sn * 4);
    float4 r = *reinterpret_cast<const float4*>(er + dn * 4);
    const float* lp = reinterpret_cast<const float*>(&l);
    const float* rp = reinterpret_cast<const float*>(&r);
    #pragma unroll
    for (int hh = 0; hh < HEADS; ++hh) {
        float sc = lp[hh] + rp[hh];
        sc = sc > 0.f ? sc : NEG_SLOPE * sc;
        float mm = fdec(m[dn * 4 + hh]);
        atomicAdd(s + dn * 4 + hh, __expf(sc - mm));
    }
}

// K5: out[dst] += alpha * feat[src]   (64 threads per edge)
__global__ __launch_bounds__(256) void gat_aggregate(
    const int* __restrict__ src, const int* __restrict__ dst,
    const float* __restrict__ el, const float* __restrict__ er,
    const unsigned int* __restrict__ m, const float* __restrict__ s,
    const float* __restrict__ feat, float* __restrict__ out) {
    int e = blockIdx.x * 4 + (threadIdx.x >> 6);
    if (e >= N_EDGES) return;
    const int o = threadIdx.x & 63;
    const int hh = o >> 4;
    const int sn = src[e], dn = dst[e];
    float sc = el[sn * 4 + hh] + er[dn * 4 + hh];
    sc = sc > 0.f ? sc : NEG_SLOPE * sc;
    const float mm = fdec(m[dn * 4 + hh]);
    const float ss = s[dn * 4 + hh];
    const float alpha = __expf(sc - mm) / (ss > 0.f ? ss : 1.f);
    const float val = feat[(size_t)sn * OUT_DIM + o] * alpha;
    atomicAdd(out + (size_t)dn * OUT_DIM + o, val);
}

extern "C" void kernel_launch(void* const* d_in, const int* in_sizes, int n_in,
                              void* d_out, int out_size, void* d_ws, size_t ws_size,
                              hipStream_t stream) {
    const float* h      = (const float*)d_in[0];
    const float* W      = (const float*)d_in[1];
    const float* attn_l = (const float*)d_in[2];
    const float* attn_r = (const float*)d_in[3];
    const float* bias   = (const float*)d_in[4];
    const int*   src    = (const int*)d_in[5];
    const int*   dst    = (const int*)d_in[6];
    float* out = (float*)d_out;

    float* feat = (float*)d_ws;                       // 100000*64 f32 = 25.6 MB
    float* el   = feat + (size_t)N_NODES * OUT_DIM;   // 1.6 MB
    float* er   = el + (size_t)N_NODES * HEADS;       // 1.6 MB
    unsigned int* m = (unsigned int*)(er + (size_t)N_NODES * HEADS); // 1.6 MB
    float* s    = (float*)(m + (size_t)N_NODES * HEADS);             // 1.6 MB

    gat_gemm<<<N_NODES / 16, 256, 0, stream>>>(h, W, attn_l, attn_r, feat, el, er);
    gat_init<<<(N_NODES * OUT_DIM + 255) / 256, 256, 0, stream>>>(out, bias, m, s);
    gat_edge_max<<<(N_EDGES + 255) / 256, 256, 0, stream>>>(src, dst, el, er, m);
    gat_edge_sum<<<(N_EDGES + 255) / 256, 256, 0, stream>>>(src, dst, el, er, m, s);
    gat_aggregate<<<N_EDGES / 4, 256, 0, stream>>>(src, dst, el, er, m, s, feat, out);
}

// Round 2
// 707.194 us; speedup vs baseline: 2.7677x; 2.7677x over previous
//
#include <hip/hip_runtime.h>

#define N_NODES 100000
#define N_EDGES 3200000
#define IN_DIM  128
#define HEADS   4
#define OUT_DIM 64   // HEADS * 16
#define NEG_SLOPE 0.2f
#define NBLK_SCAN 391   // ceil(N_NODES / 256)

// ---------------------------------------------------------------------------
// K1: feat = h @ W^T  (+ fused el/er head-dots)
// Block tile: 64 nodes x 64 outs, 256 threads as 16(tx=out)x16(ty=node),
// 4x4 register microtile. W read from global (32KB, L1-resident).
// h staged in LDS, stride 132 floats keeps float4 alignment, conflicts ~free.
// ---------------------------------------------------------------------------
__global__ __launch_bounds__(256) void gat_gemm(
    const float* __restrict__ h, const float* __restrict__ W,
    const float* __restrict__ attn_l, const float* __restrict__ attn_r,
    float* __restrict__ feat, float* __restrict__ el, float* __restrict__ er)
{
    __shared__ float Hs[64][IN_DIM + 4];   // 33.8 KB
    const int tid  = threadIdx.x;
    const int base = blockIdx.x * 64;

    // stage 64 h-rows: lane c=tid&31 covers float4-col, r=tid>>5 row, 8 passes
    const int c = tid & 31;
    #pragma unroll
    for (int it = 0; it < 8; ++it) {
        int r = (tid >> 5) + 8 * it;
        int gn = base + r; if (gn >= N_NODES) gn = N_NODES - 1;
        float4 v = *reinterpret_cast<const float4*>(h + (size_t)gn * IN_DIM + 4 * c);
        *reinterpret_cast<float4*>(&Hs[r][4 * c]) = v;
    }
    __syncthreads();

    const int tx = tid & 15;          // out group: o0 = 4*tx
    const int ty = tid >> 4;          // node group: n0 = 4*ty
    const int o0 = 4 * tx;
    const int n0 = 4 * ty;

    float acc[4][4];
    #pragma unroll
    for (int j = 0; j < 4; ++j)
        #pragma unroll
        for (int i = 0; i < 4; ++i) acc[j][i] = 0.f;

    #pragma unroll 2
    for (int kq = 0; kq < IN_DIM / 4; ++kq) {
        float4 hv[4], wv[4];
        #pragma unroll
        for (int j = 0; j < 4; ++j)
            hv[j] = *reinterpret_cast<const float4*>(&Hs[n0 + j][4 * kq]);
        #pragma unroll
        for (int i = 0; i < 4; ++i)
            wv[i] = *reinterpret_cast<const float4*>(W + (size_t)(o0 + i) * IN_DIM + 4 * kq);
        #pragma unroll
        for (int j = 0; j < 4; ++j) {
            #pragma unroll
            for (int i = 0; i < 4; ++i) {
                acc[j][i] = fmaf(hv[j].x, wv[i].x, acc[j][i]);
                acc[j][i] = fmaf(hv[j].y, wv[i].y, acc[j][i]);
                acc[j][i] = fmaf(hv[j].z, wv[i].z, acc[j][i]);
                acc[j][i] = fmaf(hv[j].w, wv[i].w, acc[j][i]);
            }
        }
    }

    float al[4], ar[4];
    #pragma unroll
    for (int i = 0; i < 4; ++i) { al[i] = attn_l[o0 + i]; ar[i] = attn_r[o0 + i]; }

    #pragma unroll
    for (int j = 0; j < 4; ++j) {
        const int n = base + n0 + j;
        float vl = 0.f, vr = 0.f;
        #pragma unroll
        for (int i = 0; i < 4; ++i) {
            vl = fmaf(acc[j][i], al[i], vl);
            vr = fmaf(acc[j][i], ar[i], vr);
        }
        // sum over the 4 tx-lanes of this head (lane bits 0-1 = tx bits 0-1)
        vl += __shfl_xor(vl, 1); vl += __shfl_xor(vl, 2);
        vr += __shfl_xor(vr, 1); vr += __shfl_xor(vr, 2);
        if (n < N_NODES) {
            *reinterpret_cast<float4*>(feat + (size_t)n * OUT_DIM + o0) =
                make_float4(acc[j][0], acc[j][1], acc[j][2], acc[j][3]);
            if ((tx & 3) == 0) {
                const int hh = tx >> 2;
                el[n * HEADS + hh] = vl;
                er[n * HEADS + hh] = vr;
            }
        }
    }
}

// ---------------------------------------------------------------------------
// K2: in-degree histogram (int atomics, 400KB L2-resident)
// ---------------------------------------------------------------------------
__global__ __launch_bounds__(256) void gat_hist(
    const int* __restrict__ dst, int* __restrict__ counts)
{
    int e = blockIdx.x * 256 + threadIdx.x;
    if (e < N_EDGES) atomicAdd(counts + dst[e], 1);
}

// ---------------------------------------------------------------------------
// K3a/b/c: exclusive scan of counts -> offs (block scan + block-sum scan + add)
// ---------------------------------------------------------------------------
__global__ __launch_bounds__(256) void gat_scanA(
    const int* __restrict__ counts, int* __restrict__ offs, int* __restrict__ bsum)
{
    __shared__ int sm[256];
    const int tid = threadIdx.x;
    const int i = blockIdx.x * 256 + tid;
    int v = (i < N_NODES) ? counts[i] : 0;
    sm[tid] = v;
    __syncthreads();
    for (int off = 1; off < 256; off <<= 1) {
        int t = (tid >= off) ? sm[tid - off] : 0;
        __syncthreads();
        sm[tid] += t;
        __syncthreads();
    }
    if (i < N_NODES) offs[i] = sm[tid] - v;          // exclusive within block
    if (tid == 255) bsum[blockIdx.x] = sm[255];      // block total
}

__global__ __launch_bounds__(512) void gat_scanB(int* __restrict__ bsum)
{
    __shared__ int sm[512];
    const int tid = threadIdx.x;
    int v = (tid < NBLK_SCAN) ? bsum[tid] : 0;
    sm[tid] = v;
    __syncthreads();
    for (int off = 1; off < 512; off <<= 1) {
        int t = (tid >= off) ? sm[tid - off] : 0;
        __syncthreads();
        sm[tid] += t;
        __syncthreads();
    }
    if (tid < NBLK_SCAN) bsum[tid] = sm[tid] - v;    // exclusive, in place
}

__global__ __launch_bounds__(256) void gat_scanC(
    int* __restrict__ offs, const int* __restrict__ bsum, int* __restrict__ cursor)
{
    const int i = blockIdx.x * 256 + threadIdx.x;
    if (i < N_NODES) {
        int o = offs[i] + bsum[blockIdx.x];
        offs[i] = o;
        cursor[i] = o;
    }
    if (blockIdx.x == 0 && threadIdx.x == 0) offs[N_NODES] = N_EDGES;
}

// ---------------------------------------------------------------------------
// K4: scatter edges into CSR order by dst
// ---------------------------------------------------------------------------
__global__ __launch_bounds__(256) void gat_scatter(
    const int* __restrict__ src, const int* __restrict__ dst,
    int* __restrict__ cursor, int* __restrict__ csr_src)
{
    int e = blockIdx.x * 256 + threadIdx.x;
    if (e >= N_EDGES) return;
    int dn = dst[e];
    int pos = atomicAdd(cursor + dn, 1);
    csr_src[pos] = src[e];
}

// ---------------------------------------------------------------------------
// K5: one wave per node, online softmax in registers, zero float atomics.
// lane o = output feature, hh = o>>4 = head.
// ---------------------------------------------------------------------------
__global__ __launch_bounds__(256) void gat_aggregate(
    const int* __restrict__ offs, const int* __restrict__ csr_src,
    const float* __restrict__ el, const float* __restrict__ er,
    const float* __restrict__ feat, const float* __restrict__ bias,
    float* __restrict__ out)
{
    const int n = blockIdx.x * 4 + (threadIdx.x >> 6);
    if (n >= N_NODES) return;
    const int lane = threadIdx.x & 63;
    const int hh = lane >> 4;

    const float erd = er[n * HEADS + hh];
    const float bo  = bias[lane];
    const int beg = offs[n], end = offs[n + 1];

    float mrun = -1e30f, ssum = 0.f, acc = 0.f;

    for (int c = beg; c < end; c += 64) {
        const int nvalid = min(64, end - c);
        int mysrc = (lane < nvalid) ? csr_src[c + lane] : 0;
        for (int j = 0; j < nvalid; ++j) {
            const int s = __shfl(mysrc, j);
            float sc = el[s * HEADS + hh] + erd;
            sc = sc > 0.f ? sc : NEG_SLOPE * sc;
            if (sc > mrun) {
                const float r = __expf(mrun - sc);
                ssum *= r; acc *= r; mrun = sc;
            }
            const float p = __expf(sc - mrun);
            ssum += p;
            acc = fmaf(p, feat[(size_t)s * OUT_DIM + lane], acc);
        }
    }
    out[(size_t)n * OUT_DIM + lane] = acc / (ssum > 0.f ? ssum : 1.f) + bo;
}

// ---------------------------------------------------------------------------
extern "C" void kernel_launch(void* const* d_in, const int* in_sizes, int n_in,
                              void* d_out, int out_size, void* d_ws, size_t ws_size,
                              hipStream_t stream) {
    const float* h      = (const float*)d_in[0];
    const float* W      = (const float*)d_in[1];
    const float* attn_l = (const float*)d_in[2];
    const float* attn_r = (const float*)d_in[3];
    const float* bias   = (const float*)d_in[4];
    const int*   src    = (const int*)d_in[5];
    const int*   dst    = (const int*)d_in[6];
    float* out = (float*)d_out;

    float* feat   = (float*)d_ws;                              // 6,400,000 f32
    float* el     = feat + (size_t)N_NODES * OUT_DIM;          // 400,000
    float* er     = el + (size_t)N_NODES * HEADS;              // 400,000
    int*   counts = (int*)(er + (size_t)N_NODES * HEADS);      // 100,000
    int*   offs   = counts + N_NODES;                          // 100,001
    int*   cursor = offs + (N_NODES + 1);                      // 100,000
    int*   bsum   = cursor + N_NODES;                          // 512
    int*   csr    = bsum + 512;                                // 3,200,000
    // total ~42.4 MB

    hipMemsetAsync(counts, 0, (size_t)N_NODES * sizeof(int), stream);

    gat_gemm<<<(N_NODES + 63) / 64, 256, 0, stream>>>(h, W, attn_l, attn_r, feat, el, er);
    gat_hist<<<(N_EDGES + 255) / 256, 256, 0, stream>>>(dst, counts);
    gat_scanA<<<NBLK_SCAN, 256, 0, stream>>>(counts, offs, bsum);
    gat_scanB<<<1, 512, 0, stream>>>(bsum);
    gat_scanC<<<NBLK_SCAN, 256, 0, stream>>>(offs, bsum, cursor);
    gat_scatter<<<(N_EDGES + 255) / 256, 256, 0, stream>>>(src, dst, cursor, csr);
    gat_aggregate<<<(N_NODES + 3) / 4, 256, 0, stream>>>(offs, csr, el, er, feat, bias, out);
}

// Round 3
// 506.726 us; speedup vs baseline: 3.8626x; 1.3956x over previous
//
#include <hip/hip_runtime.h>

#define N_NODES 100000
#define N_EDGES 3200000
#define IN_DIM  128
#define HEADS   4
#define OUT_DIM 64   // HEADS * 16
#define NEG_SLOPE 0.2f
#define NBLK_SCAN 391   // ceil(N_NODES / 256)
#define NBUCK 196       // ceil(N_NODES / 512)
#define BSH 9           // bucket shift: 512 nodes per bucket
#define CHUNK 8192      // edges per gat_bin block

__device__ inline float wmax64(float v) {
    #pragma unroll
    for (int o = 32; o; o >>= 1) v = fmaxf(v, __shfl_xor(v, o));
    return v;
}
__device__ inline float wsum64(float v) {
    #pragma unroll
    for (int o = 32; o; o >>= 1) v += __shfl_xor(v, o);
    return v;
}

// ---------------------------------------------------------------------------
// K1: feat = h @ W^T  (+ fused el/er head-dots). 64x64 tile, 4x4 microtile.
// ---------------------------------------------------------------------------
__global__ __launch_bounds__(256) void gat_gemm(
    const float* __restrict__ h, const float* __restrict__ W,
    const float* __restrict__ attn_l, const float* __restrict__ attn_r,
    float* __restrict__ feat, float* __restrict__ el, float* __restrict__ er)
{
    __shared__ float Hs[64][IN_DIM + 4];
    const int tid  = threadIdx.x;
    const int base = blockIdx.x * 64;

    const int c = tid & 31;
    #pragma unroll
    for (int it = 0; it < 8; ++it) {
        int r = (tid >> 5) + 8 * it;
        int gn = base + r; if (gn >= N_NODES) gn = N_NODES - 1;
        float4 v = *reinterpret_cast<const float4*>(h + (size_t)gn * IN_DIM + 4 * c);
        *reinterpret_cast<float4*>(&Hs[r][4 * c]) = v;
    }
    __syncthreads();

    const int tx = tid & 15, ty = tid >> 4;
    const int o0 = 4 * tx, n0 = 4 * ty;

    float acc[4][4];
    #pragma unroll
    for (int j = 0; j < 4; ++j)
        #pragma unroll
        for (int i = 0; i < 4; ++i) acc[j][i] = 0.f;

    #pragma unroll 2
    for (int kq = 0; kq < IN_DIM / 4; ++kq) {
        float4 hv[4], wv[4];
        #pragma unroll
        for (int j = 0; j < 4; ++j)
            hv[j] = *reinterpret_cast<const float4*>(&Hs[n0 + j][4 * kq]);
        #pragma unroll
        for (int i = 0; i < 4; ++i)
            wv[i] = *reinterpret_cast<const float4*>(W + (size_t)(o0 + i) * IN_DIM + 4 * kq);
        #pragma unroll
        for (int j = 0; j < 4; ++j) {
            #pragma unroll
            for (int i = 0; i < 4; ++i) {
                acc[j][i] = fmaf(hv[j].x, wv[i].x, acc[j][i]);
                acc[j][i] = fmaf(hv[j].y, wv[i].y, acc[j][i]);
                acc[j][i] = fmaf(hv[j].z, wv[i].z, acc[j][i]);
                acc[j][i] = fmaf(hv[j].w, wv[i].w, acc[j][i]);
            }
        }
    }

    float al[4], ar[4];
    #pragma unroll
    for (int i = 0; i < 4; ++i) { al[i] = attn_l[o0 + i]; ar[i] = attn_r[o0 + i]; }

    #pragma unroll
    for (int j = 0; j < 4; ++j) {
        const int n = base + n0 + j;
        float vl = 0.f, vr = 0.f;
        #pragma unroll
        for (int i = 0; i < 4; ++i) {
            vl = fmaf(acc[j][i], al[i], vl);
            vr = fmaf(acc[j][i], ar[i], vr);
        }
        vl += __shfl_xor(vl, 1); vl += __shfl_xor(vl, 2);
        vr += __shfl_xor(vr, 1); vr += __shfl_xor(vr, 2);
        if (n < N_NODES) {
            *reinterpret_cast<float4*>(feat + (size_t)n * OUT_DIM + o0) =
                make_float4(acc[j][0], acc[j][1], acc[j][2], acc[j][3]);
            if ((tx & 3) == 0) {
                const int hh = tx >> 2;
                el[n * HEADS + hh] = vl;
                er[n * HEADS + hh] = vr;
            }
        }
    }
}

// ---------------------------------------------------------------------------
// K2: in-degree histogram
// ---------------------------------------------------------------------------
__global__ __launch_bounds__(256) void gat_hist(
    const int* __restrict__ dst, int* __restrict__ counts)
{
    int e = blockIdx.x * 256 + threadIdx.x;
    if (e < N_EDGES) atomicAdd(counts + dst[e], 1);
}

// ---------------------------------------------------------------------------
// K3a/b/c: exclusive scan of counts -> offs; init cursor + bucket cursors
// ---------------------------------------------------------------------------
__global__ __launch_bounds__(256) void gat_scanA(
    const int* __restrict__ counts, int* __restrict__ offs, int* __restrict__ bsum)
{
    __shared__ int sm[256];
    const int tid = threadIdx.x;
    const int i = blockIdx.x * 256 + tid;
    int v = (i < N_NODES) ? counts[i] : 0;
    sm[tid] = v;
    __syncthreads();
    for (int off = 1; off < 256; off <<= 1) {
        int t = (tid >= off) ? sm[tid - off] : 0;
        __syncthreads();
        sm[tid] += t;
        __syncthreads();
    }
    if (i < N_NODES) offs[i] = sm[tid] - v;
    if (tid == 255) bsum[blockIdx.x] = sm[255];
}

__global__ __launch_bounds__(512) void gat_scanB(int* __restrict__ bsum)
{
    __shared__ int sm[512];
    const int tid = threadIdx.x;
    int v = (tid < NBLK_SCAN) ? bsum[tid] : 0;
    sm[tid] = v;
    __syncthreads();
    for (int off = 1; off < 512; off <<= 1) {
        int t = (tid >= off) ? sm[tid - off] : 0;
        __syncthreads();
        sm[tid] += t;
        __syncthreads();
    }
    if (tid < NBLK_SCAN) bsum[tid] = sm[tid] - v;
}

__global__ __launch_bounds__(256) void gat_scanC(
    int* __restrict__ offs, const int* __restrict__ bsum,
    int* __restrict__ cursor, int* __restrict__ bcur)
{
    const int i = blockIdx.x * 256 + threadIdx.x;
    if (i < N_NODES) {
        int o = offs[i] + bsum[blockIdx.x];
        offs[i] = o;
        cursor[i] = o;
        if ((i & ((1 << BSH) - 1)) == 0) bcur[i >> BSH] = o;
    }
    if (blockIdx.x == 0 && threadIdx.x == 0) offs[N_NODES] = N_EDGES;
}

// ---------------------------------------------------------------------------
// K4a: coarse binning — pack (src<<9 | dst&511) into bucket-contiguous runs
// ---------------------------------------------------------------------------
__global__ __launch_bounds__(256) void gat_bin(
    const int* __restrict__ src, const int* __restrict__ dst,
    int* __restrict__ bcur, unsigned int* __restrict__ binned)
{
    __shared__ int cnt[NBUCK];
    __shared__ int boff[NBUCK];
    const int tid  = threadIdx.x;
    const int base = blockIdx.x * CHUNK;
    const int nval = min(CHUNK, N_EDGES - base);

    for (int i = tid; i < NBUCK; i += 256) cnt[i] = 0;
    __syncthreads();
    for (int i = tid; i < nval; i += 256)
        atomicAdd(&cnt[dst[base + i] >> BSH], 1);
    __syncthreads();
    for (int i = tid; i < NBUCK; i += 256)
        boff[i] = atomicAdd(&bcur[i], cnt[i]);
    __syncthreads();
    for (int i = tid; i < nval; i += 256) {
        int d = dst[base + i], s = src[base + i];
        int slot = atomicAdd(&boff[d >> BSH], 1);
        binned[slot] = ((unsigned)s << BSH) | (unsigned)(d & ((1 << BSH) - 1));
    }
}

// ---------------------------------------------------------------------------
// K4b: fine scatter within each bucket (writes confined to ~64KB L2 window)
// ---------------------------------------------------------------------------
#define SUBB 8
__global__ __launch_bounds__(256) void gat_fine(
    const unsigned int* __restrict__ binned, const int* __restrict__ offs,
    int* __restrict__ cursor, int* __restrict__ csr)
{
    const int b   = blockIdx.x / SUBB;
    const int sub = blockIdx.x % SUBB;
    const int nodebase = b << BSH;
    const int nb  = min(nodebase + (1 << BSH), N_NODES);
    const int beg = offs[nodebase], end = offs[nb];
    for (int i = beg + sub * 256 + threadIdx.x; i < end; i += SUBB * 256) {
        unsigned v = binned[i];
        int d = nodebase + (int)(v & ((1u << BSH) - 1));
        int pos = atomicAdd(&cursor[d], 1);
        csr[pos] = (int)(v >> BSH);
    }
}

// ---------------------------------------------------------------------------
// K5: one wave per node; wave-parallel online softmax, LDS-staged (p,src),
// tight fma aggregation loop. Zero float atomics.
// ---------------------------------------------------------------------------
__global__ __launch_bounds__(256) void gat_aggregate(
    const int* __restrict__ offs, const int* __restrict__ csr_src,
    const float* __restrict__ el, const float* __restrict__ er,
    const float* __restrict__ feat, const float* __restrict__ bias,
    float* __restrict__ out)
{
    __shared__ float pb[4][4 * 65];   // [wave][h*65 + j]  (stride 65: no bank conflict)
    __shared__ int   sb[4][64];       // [wave][j]
    const int w = threadIdx.x >> 6;
    const int n = blockIdx.x * 4 + w;
    if (n >= N_NODES) return;
    const int lane = threadIdx.x & 63;
    const int hh = lane >> 4;

    const float4 er4 = *reinterpret_cast<const float4*>(er + n * 4);
    const float bo = bias[lane];
    const int beg = offs[n], end = offs[n + 1];

    float m0 = -1e30f, m1 = -1e30f, m2 = -1e30f, m3 = -1e30f;
    float ssum = 0.f, acc = 0.f;      // per-lane: head hh only

    for (int c = beg; c < end; c += 64) {
        const int nvalid = min(64, end - c);
        const bool act = lane < nvalid;
        const int mysrc = act ? csr_src[c + lane] : 0;

        float4 el4 = *reinterpret_cast<const float4*>(el + mysrc * 4);
        float sc0 = el4.x + er4.x, sc1 = el4.y + er4.y;
        float sc2 = el4.z + er4.z, sc3 = el4.w + er4.w;
        sc0 = sc0 > 0.f ? sc0 : NEG_SLOPE * sc0;
        sc1 = sc1 > 0.f ? sc1 : NEG_SLOPE * sc1;
        sc2 = sc2 > 0.f ? sc2 : NEG_SLOPE * sc2;
        sc3 = sc3 > 0.f ? sc3 : NEG_SLOPE * sc3;
        if (!act) { sc0 = sc1 = sc2 = sc3 = -1e30f; }

        const float nm0 = fmaxf(m0, wmax64(sc0));
        const float nm1 = fmaxf(m1, wmax64(sc1));
        const float nm2 = fmaxf(m2, wmax64(sc2));
        const float nm3 = fmaxf(m3, wmax64(sc3));

        const float p0 = __expf(sc0 - nm0);
        const float p1 = __expf(sc1 - nm1);
        const float p2 = __expf(sc2 - nm2);
        const float p3 = __expf(sc3 - nm3);

        const float cs0 = wsum64(p0), cs1 = wsum64(p1);
        const float cs2 = wsum64(p2), cs3 = wsum64(p3);

        const float nm = hh == 0 ? nm0 : hh == 1 ? nm1 : hh == 2 ? nm2 : nm3;
        const float mo = hh == 0 ? m0  : hh == 1 ? m1  : hh == 2 ? m2  : m3;
        const float cs = hh == 0 ? cs0 : hh == 1 ? cs1 : hh == 2 ? cs2 : cs3;
        const float scale = __expf(mo - nm);
        ssum = ssum * scale + cs;
        acc *= scale;
        m0 = nm0; m1 = nm1; m2 = nm2; m3 = nm3;

        pb[w][0 * 65 + lane] = p0;
        pb[w][1 * 65 + lane] = p1;
        pb[w][2 * 65 + lane] = p2;
        pb[w][3 * 65 + lane] = p3;
        sb[w][lane] = mysrc;

        const float* pbh = &pb[w][hh * 65];
        for (int j = 0; j < nvalid; ++j) {
            const float p = pbh[j];
            const int s = sb[w][j];
            acc = fmaf(p, feat[(size_t)s * OUT_DIM + lane], acc);
        }
    }
    out[(size_t)n * OUT_DIM + lane] = acc / (ssum > 0.f ? ssum : 1.f) + bo;
}

// ---------------------------------------------------------------------------
extern "C" void kernel_launch(void* const* d_in, const int* in_sizes, int n_in,
                              void* d_out, int out_size, void* d_ws, size_t ws_size,
                              hipStream_t stream) {
    const float* h      = (const float*)d_in[0];
    const float* W      = (const float*)d_in[1];
    const float* attn_l = (const float*)d_in[2];
    const float* attn_r = (const float*)d_in[3];
    const float* bias   = (const float*)d_in[4];
    const int*   src    = (const int*)d_in[5];
    const int*   dst    = (const int*)d_in[6];
    float* out = (float*)d_out;

    float* feat   = (float*)d_ws;                              // 6,400,000 f32
    float* el     = feat + (size_t)N_NODES * OUT_DIM;          // 400,000
    float* er     = el + (size_t)N_NODES * HEADS;              // 400,000
    int*   counts = (int*)(er + (size_t)N_NODES * HEADS);      // 100,000
    int*   offs   = counts + N_NODES;                          // 100,001
    int*   cursor = offs + (N_NODES + 1);                      // 100,000
    int*   bsum   = cursor + N_NODES;                          // 512
    int*   bcur   = bsum + 512;                                // 256
    unsigned int* binned = (unsigned int*)(bcur + 256);        // 3,200,000
    int*   csr    = (int*)(binned + N_EDGES);                  // 3,200,000
    // total ~55.7 MB

    hipMemsetAsync(counts, 0, (size_t)N_NODES * sizeof(int), stream);

    gat_gemm<<<(N_NODES + 63) / 64, 256, 0, stream>>>(h, W, attn_l, attn_r, feat, el, er);
    gat_hist<<<(N_EDGES + 255) / 256, 256, 0, stream>>>(dst, counts);
    gat_scanA<<<NBLK_SCAN, 256, 0, stream>>>(counts, offs, bsum);
    gat_scanB<<<1, 512, 0, stream>>>(bsum);
    gat_scanC<<<NBLK_SCAN, 256, 0, stream>>>(offs, bsum, cursor, bcur);
    gat_bin<<<(N_EDGES + CHUNK - 1) / CHUNK, 256, 0, stream>>>(src, dst, bcur, binned);
    gat_fine<<<NBUCK * SUBB, 256, 0, stream>>>(binned, offs, cursor, csr);
    gat_aggregate<<<(N_NODES + 3) / 4, 256, 0, stream>>>(offs, csr, el, er, feat, bias, out);
}